// Round 4
// baseline (682.930 us; speedup 1.0000x reference)
//
#include <hip/hip_runtime.h>
#include <stdint.h>

#define NB 8192      // tokens
#define ND 2048      // input dim
#define NO 2048      // output dim
#define NE 8         // experts

typedef __bf16 bf16x8 __attribute__((ext_vector_type(8)));
typedef float floatx4 __attribute__((ext_vector_type(4)));

__device__ __forceinline__ unsigned short f2bf(float f) {
    union { float f; uint32_t u; } v; v.f = f;
    uint32_t u = v.u;
    return (unsigned short)((u + 0x7FFFu + ((u >> 16) & 1u)) >> 16);  // RNE
}

// Fused: bf16-convert x row + router logits + top-2 + softmax. One wave per token.
__global__ __launch_bounds__(256) void router_cvt_kernel(const float* __restrict__ x,
        const float* __restrict__ rw, const float* __restrict__ rb,
        unsigned short* __restrict__ xbf,
        int* __restrict__ i0a, int* __restrict__ i1a,
        float* __restrict__ w0a, float* __restrict__ w1a) {
    const int wave = threadIdx.x >> 6;
    const int lane = threadIdx.x & 63;
    const int t = blockIdx.x * 4 + wave;
    const float4* xp = (const float4*)(x + (size_t)t * ND);
    ushort4* xo = (ushort4*)(xbf + (size_t)t * ND);
    const float4* rp = (const float4*)rw;
    float acc[NE];
#pragma unroll
    for (int e = 0; e < NE; e++) acc[e] = 0.f;
#pragma unroll
    for (int i = 0; i < ND / 256; i++) {   // 8 iters: 64 lanes x float4
        int idx = i * 64 + lane;
        float4 xv = xp[idx];
        ushort4 o;
        o.x = f2bf(xv.x); o.y = f2bf(xv.y); o.z = f2bf(xv.z); o.w = f2bf(xv.w);
        xo[idx] = o;
#pragma unroll
        for (int e = 0; e < NE; e++) {
            float4 rv = rp[(size_t)e * (ND / 4) + idx];
            acc[e] += xv.x * rv.x + xv.y * rv.y + xv.z * rv.z + xv.w * rv.w;
        }
    }
#pragma unroll
    for (int e = 0; e < NE; e++) {
        float v = acc[e];
#pragma unroll
        for (int s = 32; s > 0; s >>= 1) v += __shfl_xor(v, s, 64);
        acc[e] = v;
    }
    if (lane == 0) {
        float lg[NE];
#pragma unroll
        for (int e = 0; e < NE; e++) lg[e] = acc[e] + rb[e];
        int i0 = 0; float v0 = lg[0];
#pragma unroll
        for (int e = 1; e < NE; e++) if (lg[e] > v0) { v0 = lg[e]; i0 = e; }  // first-max ties = top_k
        int i1 = -1; float v1 = -3.4e38f;
#pragma unroll
        for (int e = 0; e < NE; e++) if (e != i0 && lg[e] > v1) { v1 = lg[e]; i1 = e; }
        float ex = expf(v1 - v0);
        float inv = 1.f / (1.f + ex);
        i0a[t] = i0; i1a[t] = i1;
        w0a[t] = inv; w1a[t] = ex * inv;
    }
}

__global__ __launch_bounds__(256) void cvt_w_kernel(const float* __restrict__ in,
                                                    unsigned short* __restrict__ out, int n4) {
    int i = blockIdx.x * blockDim.x + threadIdx.x;
    int stride = gridDim.x * blockDim.x;
    for (; i < n4; i += stride) {
        float4 v = ((const float4*)in)[i];
        ushort4 o;
        o.x = f2bf(v.x); o.y = f2bf(v.y); o.z = f2bf(v.z); o.w = f2bf(v.w);
        ((ushort4*)out)[i] = o;
    }
}

// 128 global waves; per-(wave, which, expert) selection counts via ballot.
__global__ __launch_bounds__(256) void hist_kernel(
        const int* __restrict__ i0a, const int* __restrict__ i1a,
        int* __restrict__ waveCnt) {
    const int lane = threadIdx.x & 63;
    const int gw = (blockIdx.x * 256 + threadIdx.x) >> 6;   // 0..127
    const int t = gw * 64 + lane;
#pragma unroll
    for (int which = 0; which < 2; which++) {
        int sel = which ? i1a[t] : i0a[t];
        unsigned long long m[NE];
#pragma unroll
        for (int e = 0; e < NE; e++) m[e] = __ballot(sel == e);
        if (lane < NE)
            waveCnt[lane * 256 + which * 128 + gw] = (int)__popcll(m[lane]);
    }
}

// Exclusive scan of 256 values per expert (primary gw 0..127, then secondary).
__global__ __launch_bounds__(256) void scan_kernel(const int* __restrict__ waveCnt,
        int* __restrict__ waveBase, int* __restrict__ cnt) {
    __shared__ int vals[2048];
    __shared__ int partials[256];
    const int tid = threadIdx.x;
    for (int i = tid; i < 2048; i += 256) vals[i] = waveCnt[i];
    __syncthreads();
    const int e = tid >> 5, c = tid & 31;   // 8 experts x 32 chunks of 8
    int local[8];
    int s = 0;
#pragma unroll
    for (int j = 0; j < 8; j++) { local[j] = s; s += vals[e * 256 + c * 8 + j]; }
    partials[e * 32 + c] = s;
    __syncthreads();
    for (int d = 1; d < 32; d <<= 1) {
        int v = partials[e * 32 + c];
        int add = (c >= d) ? partials[e * 32 + c - d] : 0;
        __syncthreads();
        partials[e * 32 + c] = v + add;
        __syncthreads();
    }
    int base = (c > 0) ? partials[e * 32 + c - 1] : 0;
#pragma unroll
    for (int j = 0; j < 8; j++) waveBase[e * 256 + c * 8 + j] = base + local[j];
    if (c == 31) cnt[e] = partials[e * 32 + 31];
}

// Deterministic scatter into combined per-expert lists (token-ascending per sublist).
__global__ __launch_bounds__(256) void scatter_kernel(
        const int* __restrict__ i0a, const int* __restrict__ i1a,
        const float* __restrict__ w0a, const float* __restrict__ w1a,
        const int* __restrict__ waveBase,
        int* __restrict__ tokC, float* __restrict__ wC) {
    const int lane = threadIdx.x & 63;
    const int gw = (blockIdx.x * 256 + threadIdx.x) >> 6;
    const int t = gw * 64 + lane;
#pragma unroll
    for (int which = 0; which < 2; which++) {
        int sel = which ? i1a[t] : i0a[t];
        float w = which ? w1a[t] : w0a[t];
        unsigned long long m[NE];
#pragma unroll
        for (int e = 0; e < NE; e++) m[e] = __ballot(sel == e);
        int slot = __popcll(m[sel] & ((1ull << lane) - 1ull));
        int base = waveBase[sel * 256 + which * 128 + gw];
        tokC[sel * NB + base + slot] = t;
        wC[sel * NB + base + slot] = w;
    }
}

#define GLL16(g, l) __builtin_amdgcn_global_load_lds( \
    (const __attribute__((address_space(1))) void*)(g), \
    (__attribute__((address_space(3))) void*)(l), 16, 0, 0)

// Single-pass gathered 128x128 GEMM, BK=64, XOR-swizzled LDS (conflict-free
// ds_read_b128), bf16 MFMA 16x16x32, atomicAdd epilogue (out pre-zeroed).
// LDS chunk c<->(row=c>>3, kchunk=(c&7)^(row&7)); reader offset row*64+((q^(row&7))*8).
__global__ __launch_bounds__(256, 4) void moe_gemm_kernel(
        const unsigned short* __restrict__ xbf, const unsigned short* __restrict__ wbf,
        const float* __restrict__ eb, const int* __restrict__ cntArr,
        const int* __restrict__ listTok, const float* __restrict__ listW,
        float* __restrict__ out) {
    __shared__ unsigned short sA[128 * 64];
    __shared__ unsigned short sB[128 * 64];
    __shared__ int sTok[128];
    __shared__ float sW[128];

    const int e = blockIdx.z, mt = blockIdx.y, nt = blockIdx.x;
    const int cnt = cntArr[e];
    if (mt * 128 >= cnt) return;
    const int tid = threadIdx.x;
    if (tid < 128) {
        int r = mt * 128 + tid;
        bool ok = r < cnt;
        sTok[tid] = ok ? listTok[e * NB + r] : 0;   // row 0 as safe dummy; masked at store
        sW[tid]   = ok ? listW[e * NB + r] : 0.f;
    }
    __syncthreads();

    // staging: 1024 chunks of 16B per operand per K-tile (128 rows x 128B); 4/thread
    const char* gA[4]; const char* gB[4];
    unsigned short* lA[4]; unsigned short* lB[4];
#pragma unroll
    for (int r = 0; r < 4; r++) {
        int c = r * 256 + tid;
        int row = c >> 3;
        int kc = (c & 7) ^ (row & 7);      // XOR swizzle
        gA[r] = (const char*)xbf + (size_t)sTok[row] * (ND * 2) + kc * 16;
        gB[r] = (const char*)wbf + ((size_t)e * NO + (size_t)nt * 128 + row) * (ND * 2) + kc * 16;
        lA[r] = sA + c * 8;
        lB[r] = sB + c * 8;
    }

    const int wave = tid >> 6, lane = tid & 63;
    const int wm = (wave >> 1) * 64, wn = (wave & 1) * 64;   // 2x2 wave grid, 64x64 each
    const int lr = lane & 15, lq = lane >> 4;

    floatx4 acc[4][4];
#pragma unroll
    for (int mi = 0; mi < 4; mi++)
#pragma unroll
        for (int nj = 0; nj < 4; nj++) acc[mi][nj] = (floatx4){0.f, 0.f, 0.f, 0.f};

    for (int kk = 0; kk < ND / 64; kk++) {
#pragma unroll
        for (int r = 0; r < 4; r++) {
            GLL16(gA[r], lA[r]);
            GLL16(gB[r], lB[r]);
            gA[r] += 128; gB[r] += 128;   // advance K by 64 bf16
        }
        __syncthreads();
#pragma unroll
        for (int s = 0; s < 2; s++) {
            bf16x8 af[4], bfr[4];
#pragma unroll
            for (int mi = 0; mi < 4; mi++) {
                int m = wm + mi * 16 + lr, q = s * 4 + lq;
                af[mi] = *(const bf16x8*)&sA[m * 64 + ((q ^ (m & 7)) * 8)];
            }
#pragma unroll
            for (int nj = 0; nj < 4; nj++) {
                int n = wn + nj * 16 + lr, q = s * 4 + lq;
                bfr[nj] = *(const bf16x8*)&sB[n * 64 + ((q ^ (n & 7)) * 8)];
            }
#pragma unroll
            for (int mi = 0; mi < 4; mi++)
#pragma unroll
                for (int nj = 0; nj < 4; nj++)
                    acc[mi][nj] = __builtin_amdgcn_mfma_f32_16x16x32_bf16(af[mi], bfr[nj], acc[mi][nj], 0, 0, 0);
        }
        __syncthreads();
    }

    // epilogue: C/D layout col=lane&15, row=(lane>>4)*4+reg; exactly-2 adds/element
#pragma unroll
    for (int nj = 0; nj < 4; nj++) {
        int gn = nt * 128 + wn + nj * 16 + lr;
        float bias = eb[(size_t)e * NO + gn];
#pragma unroll
        for (int mi = 0; mi < 4; mi++) {
#pragma unroll
            for (int r = 0; r < 4; r++) {
                int m = wm + mi * 16 + lq * 4 + r;
                if (mt * 128 + m < cnt) {
                    atomicAdd(out + (size_t)sTok[m] * NO + gn, sW[m] * (acc[mi][nj][r] + bias));
                }
            }
        }
    }
}

extern "C" void kernel_launch(void* const* d_in, const int* in_sizes, int n_in,
                              void* d_out, int out_size, void* d_ws, size_t ws_size,
                              hipStream_t stream) {
    const float* x        = (const float*)d_in[0];
    const float* router_w = (const float*)d_in[1];
    const float* router_b = (const float*)d_in[2];
    const float* expert_w = (const float*)d_in[3];
    const float* expert_b = (const float*)d_in[4];
    float* out = (float*)d_out;
    char* ws = (char*)d_ws;

    unsigned short* xbf = (unsigned short*)ws;                 // 33,554,432 B
    unsigned short* wbf = (unsigned short*)(ws + 33554432);    // 67,108,864 B -> ends 100,663,296
    size_t o = 100663296;
    int*   tokC = (int*)(ws + o);     o += NE * NB * 4;        // 256 KB
    float* wC   = (float*)(ws + o);   o += NE * NB * 4;        // 256 KB
    int*   i0a  = (int*)(ws + o);     o += NB * 4;
    int*   i1a  = (int*)(ws + o);     o += NB * 4;
    float* w0a  = (float*)(ws + o);   o += NB * 4;
    float* w1a  = (float*)(ws + o);   o += NB * 4;
    int*   waveCnt  = (int*)(ws + o); o += 2048 * 4;
    int*   waveBase = (int*)(ws + o); o += 2048 * 4;
    int*   cnt  = (int*)(ws + o);     o += 128;
    // total ws use: ~96.7 MB

    hipMemsetAsync(out, 0, (size_t)out_size * sizeof(float), stream);
    router_cvt_kernel<<<NB / 4, 256, 0, stream>>>(x, router_w, router_b, xbf,
                                                  i0a, i1a, w0a, w1a);
    cvt_w_kernel<<<2048, 256, 0, stream>>>(expert_w, wbf, NE * NO * ND / 4);
    hist_kernel<<<NB / 64 / 4, 256, 0, stream>>>(i0a, i1a, waveCnt);
    scan_kernel<<<1, 256, 0, stream>>>(waveCnt, waveBase, cnt);
    scatter_kernel<<<NB / 64 / 4, 256, 0, stream>>>(i0a, i1a, w0a, w1a, waveBase, tokC, wC);
    moe_gemm_kernel<<<dim3(NO / 128, NB / 128, NE), 256, 0, stream>>>(
        xbf, wbf, expert_b, cnt, tokC, wC, out);
}